// Round 6
// baseline (339.745 us; speedup 1.0000x reference)
//
#include <hip/hip_runtime.h>

// Problem constants (fixed by setup_inputs)
#define BB 16
#define CC 128
#define DD 3
#define NN 4096
#define KK 1024           // NN / topk, topk = 4
#define BN (BB * NN)      // 65536
#define CH 512            // m-chunk length in k_count

// ---------------------------------------------------------------------------
// A: fused moments + score, ONE pass over fx/fy.
//   s[b,n] = xhat . M . yhat,  M[d][e] = sum_c fx[c,d]*fy[c,e]  (fp64 exact:
//   fp32*fp32 products are exact in fp64), xhat = mean/(||mean||+1e-6).
// Block = 256 threads = 32 consecutive n x 8 c-chunks of 16.
// grid = 2048 -> 8 blocks/CU (latency-bound fix: 2x waves vs R3's 4/CU).
// LDS tree reduce in 15 KB so LDS doesn't cap occupancy below 8 blocks/CU.
// Emits monotonic u64 key (descending s == descending u) and zeroes cnt.
// ---------------------------------------------------------------------------
__global__ __launch_bounds__(256) void k_moments(
        const float* __restrict__ fx, const float* __restrict__ fy,
        unsigned long long* __restrict__ skey, int* __restrict__ cnt) {
    __shared__ double lds[4][15][32];   // 15360 B
    int t = threadIdx.x;
    int p = t & 31;                   // n-slot within block
    int q = t >> 5;                   // c-chunk 0..7 (16 c each)
    int gpi = blockIdx.x * 32 + p;    // global (b,n) index
    int b = gpi >> 12;
    int n = gpi & (NN - 1);

    const size_t cstride = (size_t)DD * NN;                       // 12288
    size_t base = ((size_t)b * CC + (size_t)q * 16) * cstride + n;

    double sx0=0,sx1=0,sx2=0, sy0=0,sy1=0,sy2=0;
    double m00=0,m01=0,m02=0, m10=0,m11=0,m12=0, m20=0,m21=0,m22=0;
    #pragma unroll 4
    for (int c = 0; c < 16; ++c) {
        size_t o = base + (size_t)c * cstride;
        double x0 = (double)fx[o], x1 = (double)fx[o + NN], x2 = (double)fx[o + 2*NN];
        double y0 = (double)fy[o], y1 = (double)fy[o + NN], y2 = (double)fy[o + 2*NN];
        sx0 += x0; sx1 += x1; sx2 += x2;
        sy0 += y0; sy1 += y1; sy2 += y2;
        m00 += x0*y0; m01 += x0*y1; m02 += x0*y2;
        m10 += x1*y0; m11 += x1*y1; m12 += x1*y2;
        m20 += x2*y0; m21 += x2*y1; m22 += x2*y2;
    }

    #define STORE_SLOT(s) do { \
        lds[s][0][p]=sx0;  lds[s][1][p]=sx1;  lds[s][2][p]=sx2;  \
        lds[s][3][p]=sy0;  lds[s][4][p]=sy1;  lds[s][5][p]=sy2;  \
        lds[s][6][p]=m00;  lds[s][7][p]=m01;  lds[s][8][p]=m02;  \
        lds[s][9][p]=m10;  lds[s][10][p]=m11; lds[s][11][p]=m12; \
        lds[s][12][p]=m20; lds[s][13][p]=m21; lds[s][14][p]=m22; } while(0)
    #define ADD_SLOT(s) do { \
        sx0+=lds[s][0][p];  sx1+=lds[s][1][p];  sx2+=lds[s][2][p];  \
        sy0+=lds[s][3][p];  sy1+=lds[s][4][p];  sy2+=lds[s][5][p];  \
        m00+=lds[s][6][p];  m01+=lds[s][7][p];  m02+=lds[s][8][p];  \
        m10+=lds[s][9][p];  m11+=lds[s][10][p]; m12+=lds[s][11][p]; \
        m20+=lds[s][12][p]; m21+=lds[s][13][p]; m22+=lds[s][14][p]; } while(0)

    if (q >= 4) STORE_SLOT(q - 4);      // chunks 4..7 -> slots 0..3
    __syncthreads();
    if (q < 4)  ADD_SLOT(q);            // thread-chunk q absorbs chunk q+4
    __syncthreads();
    if (q >= 1 && q < 4) STORE_SLOT(q - 1);   // chunks 1..3 -> slots 0..2
    __syncthreads();
    if (q == 0) {
        ADD_SLOT(0); ADD_SLOT(1); ADD_SLOT(2);

        double mx0 = sx0*(1.0/128.0), mx1 = sx1*(1.0/128.0), mx2 = sx2*(1.0/128.0);
        double my0 = sy0*(1.0/128.0), my1 = sy1*(1.0/128.0), my2 = sy2*(1.0/128.0);
        double nx = sqrt(mx0*mx0 + mx1*mx1 + mx2*mx2) + 1e-6;
        double ny = sqrt(my0*my0 + my1*my1 + my2*my2) + 1e-6;
        double x0 = mx0/nx, x1 = mx1/nx, x2 = mx2/nx;
        double y0 = my0/ny, y1 = my1/ny, y2 = my2/ny;

        double s = x0*(y0*m00 + y1*m01 + y2*m02)
                 + x1*(y0*m10 + y1*m11 + y2*m12)
                 + x2*(y0*m20 + y1*m21 + y2*m22);

        // monotonic map: descending double order == descending u64 order
        long long bits = __double_as_longlong(s);
        unsigned long long u = (bits < 0)
            ? ~(unsigned long long)bits
            : ((unsigned long long)bits | 0x8000000000000000ULL);
        skey[gpi] = u;
        cnt[gpi] = 0;          // ws is poisoned each launch; re-init here
    }
    #undef STORE_SLOT
    #undef ADD_SLOT
}

// ---------------------------------------------------------------------------
// B: partial rank count.  rank[n] = #{ m : key[m]>key[n] or (== and m<n) }
// grid = 16 b x 16 n-chunks x 8 m-chunks = 2048 blocks -> 32 waves/CU.
// Tie term uses precomputed lim = n - m0:  (global m < n)  <=>  (m < lim).
// ---------------------------------------------------------------------------
__global__ __launch_bounds__(256) void k_count(
        const unsigned long long* __restrict__ skey, int* __restrict__ cnt) {
    __shared__ unsigned long long tile[CH];
    int b      = blockIdx.x >> 7;          // 16n x 8m = 128 blocks per batch
    int nchunk = (blockIdx.x >> 3) & 15;
    int mchunk = blockIdx.x & 7;
    const unsigned long long* srow = skey + b * NN;
    int m0 = mchunk * CH;
    for (int i = threadIdx.x; i < CH; i += 256)
        tile[i] = srow[m0 + i];
    __syncthreads();

    int n = nchunk * 256 + threadIdx.x;
    unsigned long long un = srow[n];
    int lim = n - m0;                      // m < lim  <=>  (m0+m) < n
    int c = 0;
    #pragma unroll 8
    for (int m = 0; m < CH; ++m) {
        unsigned long long um = tile[m];   // broadcast read, conflict-free
        c += (um > un);
        c += (um == un) & (m < lim);
    }
    atomicAdd(&cnt[b * NN + n], c);
}

// ---------------------------------------------------------------------------
// C: scatter-write gather.  Ranks are a permutation: every r<KK occurs for
// exactly one n, so  out[row][rank[n]] = src[row][n]  writes each output
// position exactly once.  Reads: perfectly-coalesced float4 (no idx->data
// dependent-load chain).  Writes: scattered 4B within a 4KB window, 1/4 the
// bytes of the read side, fire-and-forget.
// ---------------------------------------------------------------------------
__global__ __launch_bounds__(256) void k_gather(
        const float* __restrict__ fx, const float* __restrict__ fy,
        const int* __restrict__ cnt, float* __restrict__ out) {
    int row = blockIdx.x;                  // [0, BB*CC*DD)
    int b   = row / (CC * DD);
    const float* src = blockIdx.y ? fy : fx;
    float* dst = out + (size_t)blockIdx.y * ((size_t)BB * CC * DD * KK)
                     + (size_t)row * KK;
    const float4* s4 = (const float4*)(src + (size_t)row * NN);
    const int4*   c4 = (const int4*)(cnt + b * NN);
    #pragma unroll
    for (int i = threadIdx.x; i < NN / 4; i += 256) {
        float4 v = s4[i];
        int4   r = c4[i];
        if (r.x < KK) dst[r.x] = v.x;
        if (r.y < KK) dst[r.y] = v.y;
        if (r.z < KK) dst[r.z] = v.z;
        if (r.w < KK) dst[r.w] = v.w;
    }
}

extern "C" void kernel_launch(void* const* d_in, const int* in_sizes, int n_in,
                              void* d_out, int out_size, void* d_ws, size_t ws_size,
                              hipStream_t stream) {
    const float* fx = (const float*)d_in[0];
    const float* fy = (const float*)d_in[1];
    float* out = (float*)d_out;

    // ws layout: u64 skey[BN] (512KB) | int cnt[BN] (256KB)
    unsigned long long* skey = (unsigned long long*)d_ws;
    int* cnt = (int*)(skey + BN);

    k_moments<<<BN / 32, 256, 0, stream>>>(fx, fy, skey, cnt);
    k_count  <<<BB * 16 * 8, 256, 0, stream>>>(skey, cnt);
    k_gather <<<dim3(BB * CC * DD, 2), 256, 0, stream>>>(fx, fy, cnt, out);
}